// Round 6
// baseline (662.113 us; speedup 1.0000x reference)
//
#include <hip/hip_runtime.h>

typedef unsigned short ushort_t;
typedef __attribute__((ext_vector_type(8))) short short8;   // 8 bf16 = 4 VGPRs (MFMA A/B frag)
typedef __attribute__((ext_vector_type(4))) short short4v;  // 4 bf16 = 8B
typedef __attribute__((ext_vector_type(4))) float f32x4;    // MFMA C/D frag

#define NN 50000
#define EE 500000
#define DD 128
#define MAXT 10.0f

#define MFMA(a,b,c) __builtin_amdgcn_mfma_f32_16x16x32_bf16((a),(b),(c),0,0,0)

__device__ __forceinline__ ushort_t f2bf(float x){          // RNE float->bf16
  unsigned u = __float_as_uint(x);
  u += 0x7FFFu + ((u>>16)&1u);
  return (ushort_t)(u>>16);
}
__device__ __forceinline__ float bf2f(ushort_t u){
  return __uint_as_float(((unsigned)u)<<16);
}
__device__ __forceinline__ float sigm(float x){ return 1.0f/(1.0f+__expf(-x)); }
__device__ __forceinline__ float siluf(float x){ return x*sigm(x); }
__device__ __forceinline__ float clamp10(float x){ return fminf(fmaxf(x,-MAXT),MAXT); }

// load 8 consecutive fp32, convert to bf16x8 frag
__device__ __forceinline__ short8 ldcvt(const float* p){
  f32x4 x = *(const f32x4*)p;
  f32x4 y = *(const f32x4*)(p+4);
  short8 t;
  #pragma unroll
  for (int j=0;j<4;++j){ t[j]=(short)f2bf(x[j]); t[j+4]=(short)f2bf(y[j]); }
  return t;
}

// ---------------------------------------------------------------------------
// Fused: weight prep (blocks 0..447) + edge row count (blocks 448..2401).
// wpre mats: 0 W1a(nat) 1 W1b(nat) 2 W2(nat) 3 Wc1(sigma) 4 Wn1a 5 Wn1b
//            6 Wn2(sigma); sigma kidx = 8*(c&15)+(c>>4).
// ---------------------------------------------------------------------------
__global__ void k_prep_count(const float* __restrict__ We1, const float* __restrict__ We2,
                             const float* __restrict__ Wc1, const float* __restrict__ Wn1,
                             const float* __restrict__ Wn2, ushort_t* __restrict__ wpre,
                             const int* __restrict__ eidx, int* __restrict__ cnt)
{
  if (blockIdx.x < 448){
    int idx = blockIdx.x*256 + threadIdx.x;
    if (idx >= 7*16384) return;
    int mat = idx >> 14;
    int loc = idx & 16383;
    int n = loc >> 7;
    int kidx = loc & 127;
    int ko = 16*(kidx&7) + (kidx>>3);
    float v;
    switch(mat){
      case 0: v = We1[kidx*DD + n]; break;
      case 1: v = We1[(128+kidx)*DD + n]; break;
      case 2: v = We2[kidx*DD + n]; break;           // natural
      case 3: v = Wc1[ko*DD + n]; break;             // sigma
      case 4: v = Wn1[kidx*DD + n]; break;
      case 5: v = Wn1[(128+kidx)*DD + n]; break;
      default: v = Wn2[ko*DD + n]; break;            // sigma
    }
    int byteoff = n*256 + ((kidx*2) ^ ((n&7)<<4));   // XOR swizzle (16B granule)
    *(ushort_t*)((char*)wpre + (size_t)mat*32768 + byteoff) = f2bf(v);
  } else {
    int e = (blockIdx.x-448)*256 + threadIdx.x;
    if (e < EE) atomicAdd(&cnt[eidx[e]], 1);
  }
}

// ---------------------------------------------------------------------------
// Single-kernel offsets: per-block local scan + atomic global base.
// rowstart is NOT globally monotone (block bases arrive in arbitrary order)
// but each row's range [rowstart[n], rowstart[n]+cnt[n]) is valid/contiguous.
// ---------------------------------------------------------------------------
__global__ void k_offsets(const int* __restrict__ cnt, int* __restrict__ gbase,
                          int* __restrict__ rowstart, int* __restrict__ cursor)
{
  __shared__ int sh[256];
  __shared__ int base;
  int t = threadIdx.x;
  int i = blockIdx.x*256 + t;
  int v = (i < NN) ? cnt[i] : 0;
  sh[t] = v;
  __syncthreads();
  for (int off=1; off<256; off<<=1){
    int x = (t>=off) ? sh[t-off] : 0;
    __syncthreads();
    sh[t] += x;
    __syncthreads();
  }
  if (t == 255) base = atomicAdd(gbase, sh[255]);
  __syncthreads();
  int excl = sh[t] - v + base;
  if (i < NN){ rowstart[i] = excl; cursor[i] = excl; }
}

// ---------------------------------------------------------------------------
// GEMM helpers: wave tile = 32 rows x 64 cols x K=128.
// ---------------------------------------------------------------------------
__device__ __forceinline__ void stage(const ushort_t* __restrict__ wpre, int mat,
                                      ushort_t* Wbuf, int tid)
{
  const f32x4* src = (const f32x4*)(wpre + (size_t)mat*16384);
  f32x4* dst = (f32x4*)Wbuf;
  #pragma unroll
  for (int i=0;i<4;++i) dst[tid + 512*i] = src[tid + 512*i];
}
__device__ __forceinline__ void zacc(f32x4 acc[2][4]){
  #pragma unroll
  for (int i=0;i<2;++i)
    #pragma unroll
    for (int j=0;j<4;++j) acc[i][j] = (f32x4){0.f,0.f,0.f,0.f};
}
__device__ __forceinline__ void gemm_b16(const short8 af[2][4], const ushort_t* Wbuf,
                                         int cbase, int q, int s, f32x4 acc[2][4])
{
  #pragma unroll
  for (int kc=0;kc<4;++kc){
    const int koff = ((kc*64+q*16) ^ ((s&7)<<4));
    #pragma unroll
    for (int ct=0;ct<4;++ct){
      short8 bf = *(const short8*)((const char*)Wbuf + (cbase+ct*16+s)*256 + koff);
      acc[0][ct] = MFMA(af[0][kc],bf,acc[0][ct]);
      acc[1][ct] = MFMA(af[1][kc],bf,acc[1][ct]);
    }
  }
}
__device__ __forceinline__ void gemm_lds16(const ushort_t* ebuf, const ushort_t* Wbuf,
                                           int mbase, int cbase, int q, int s,
                                           f32x4 acc[2][4])
{
  #pragma unroll
  for (int kc=0;kc<4;++kc){
    const int koff = ((kc*64+q*16) ^ ((s&7)<<4));
    short8 a0 = *(const short8*)((const char*)ebuf + (mbase+s)*256 + koff);
    short8 a1 = *(const short8*)((const char*)ebuf + (mbase+16+s)*256 + koff);
    #pragma unroll
    for (int ct=0;ct<4;++ct){
      short8 bf = *(const short8*)((const char*)Wbuf + (cbase+ct*16+s)*256 + koff);
      acc[0][ct] = MFMA(a0,bf,acc[0][ct]);
      acc[1][ct] = MFMA(a1,bf,acc[1][ct]);
    }
  }
}

// ---------------------------------------------------------------------------
// Fused: CSR scatter (blocks 391..1367) + H1 precompute (blocks 0..390).
// H1a = h@W1a + be1 ; H1b = h@W1b   (bf16 out, N x 128 each)
// ---------------------------------------------------------------------------
__launch_bounds__(512,4)
__global__ void k_scatter_pre1(const int* __restrict__ eidx, int* __restrict__ cursor,
                               int* __restrict__ csr,
                               const float* __restrict__ h,
                               const ushort_t* __restrict__ wpre,
                               const float* __restrict__ be1,
                               ushort_t* __restrict__ H1a, ushort_t* __restrict__ H1b)
{
  __shared__ ushort_t Wbuf[16384];
  if (blockIdx.x >= 391){
    int e = (blockIdx.x-391)*512 + threadIdx.x;
    if (e < EE){
      int p = atomicAdd(&cursor[eidx[e]], 1);
      csr[p] = e;
    }
    return;
  }
  const int tid = threadIdx.x;
  const int wv = tid>>6, ln = tid&63;
  const int wm = wv&3, wn = wv>>2;
  const int q = ln>>4, s = ln&15;
  const int cbase = wn*64;
  const int n0 = blockIdx.x*128;
  const int mb = wm*32;
  const int nd0 = min(n0 + mb + s,      NN-1);
  const int nd1 = min(n0 + mb + 16 + s, NN-1);

  f32x4 acc[2][4];
  short8 af[2][4];
  zacc(acc);
  #pragma unroll
  for (int kc=0;kc<4;++kc){
    af[0][kc] = ldcvt(h + (size_t)nd0*DD + kc*32 + q*8);
    af[1][kc] = ldcvt(h + (size_t)nd1*DD + kc*32 + q*8);
  }
  stage(wpre, 0, Wbuf, tid);
  __syncthreads();
  gemm_b16(af, Wbuf, cbase, q, s, acc);
  {
    float bb[4];
    #pragma unroll
    for (int ct=0;ct<4;++ct) bb[ct]=be1[cbase+16*ct+s];
    #pragma unroll
    for (int mt=0;mt<2;++mt)
      #pragma unroll
      for (int r=0;r<4;++r){
        int n = n0 + mb + mt*16 + q*4 + r;
        if (n < NN){
          ushort_t* op = H1a + (size_t)n*DD + cbase + s;
          #pragma unroll
          for (int ct=0;ct<4;++ct) op[16*ct] = f2bf(acc[mt][ct][r] + bb[ct]);
        }
      }
  }
  zacc(acc);
  __syncthreads();
  stage(wpre, 1, Wbuf, tid);
  __syncthreads();
  gemm_b16(af, Wbuf, cbase, q, s, acc);
  {
    #pragma unroll
    for (int mt=0;mt<2;++mt)
      #pragma unroll
      for (int r=0;r<4;++r){
        int n = n0 + mb + mt*16 + q*4 + r;
        if (n < NN){
          ushort_t* op = H1b + (size_t)n*DD + cbase + s;
          #pragma unroll
          for (int ct=0;ct<4;++ct) op[16*ct] = f2bf(acc[mt][ct][r]);
        }
      }
  }
}

// ---------------------------------------------------------------------------
// Edge kernel (natural order): 128 edges/block, 8 waves 4(M) x 2(N).
// e1 = silu(H1a[row]+H1b[col]+rad*w1r) gathered from bf16 H1 (no GEMM1).
// (unchanged from round-4 verified version, 186 us)
// ---------------------------------------------------------------------------
__launch_bounds__(512,4)
__global__ void k_edge(const ushort_t* __restrict__ H1a,
                       const ushort_t* __restrict__ H1b,
                       const int* __restrict__ eidx,
                       const float* __restrict__ coord,
                       const float* __restrict__ We1,
                       const float* __restrict__ be2,
                       const float* __restrict__ Watt,
                       const float* __restrict__ batt,
                       const float* __restrict__ bc1,
                       const float* __restrict__ Wc2,
                       const ushort_t* __restrict__ wpre,
                       float* __restrict__ ef_out,
                       float* __restrict__ trans)
{
  __shared__ ushort_t Wbuf[16384];   // 32KB weight tile [n][k] swizzled
  __shared__ ushort_t ebuf[16384];   // 32KB activation tile
  __shared__ float dscr[128][2];     // cross-wave row-dot partials (1KB)
  const int tid = threadIdx.x;
  const int wv = tid>>6, ln = tid&63;
  const int wm = wv&3, wn = wv>>2;
  const int q = ln>>4, s = ln&15;
  const int cbase = wn*64;
  const int we0 = blockIdx.x*128;
  const int mb = wm*32;
  const int* rowI = eidx;
  const int* colI = eidx + EE;

  // geometry for trans write: edge we0+mb+(ln&31) (natural order)
  const int jg = we0 + mb + (ln&31);
  const int jgc = min(jg, EE-1);
  const int rg = rowI[jgc], cg = colI[jgc];
  const float cdx = coord[rg*3+0]-coord[cg*3+0];
  const float cdy = coord[rg*3+1]-coord[cg*3+1];
  const float cdz = coord[rg*3+2]-coord[cg*3+2];

  // e1 rows for this lane: edges we0+mb+s (mt0), +16+s (mt1)
  const int e0 = min(we0+mb+s,    EE-1);
  const int e1 = min(we0+mb+16+s, EE-1);
  const int r0 = rowI[e0], c0 = colI[e0];
  const int r1 = rowI[e1], c1 = colI[e1];
  float rad[2];
  { float dx=coord[r0*3+0]-coord[c0*3+0], dy=coord[r0*3+1]-coord[c0*3+1],
          dz=coord[r0*3+2]-coord[c0*3+2];
    rad[0]=dx*dx+dy*dy+dz*dz; }
  { float dx=coord[r1*3+0]-coord[c1*3+0], dy=coord[r1*3+1]-coord[c1*3+1],
          dz=coord[r1*3+2]-coord[c1*3+2];
    rad[1]=dx*dx+dy*dy+dz*dz; }

  stage(wpre, 2, Wbuf, tid);         // W2 (natural k-order)

  // ---- e1 gather epilogue -> ebuf (natural k pack, XOR-swizzled) ----------
  {
    float w[2][8];
    #pragma unroll
    for (int gi=0; gi<2; ++gi){
      const int g = wn*8 + q*2 + gi;
      const f32x4* pw = (const f32x4*)(We1 + 256*DD + g*8);
      f32x4 w0=pw[0], w1=pw[1];
      #pragma unroll
      for (int t=0;t<4;++t){ w[gi][t]=w0[t]; w[gi][t+4]=w1[t]; }
    }
    #pragma unroll
    for (int mt=0; mt<2; ++mt){
      const int nR = mt ? r1 : r0, nC = mt ? c1 : c0;
      const float rd = rad[mt];
      const int m = mb + mt*16 + s;
      #pragma unroll
      for (int gi=0; gi<2; ++gi){
        const int g = wn*8 + q*2 + gi;           // k-granule 0..15 (8 bf16 each)
        short8 sa = *(const short8*)(H1a + (size_t)nR*DD + g*8);
        short8 sb = *(const short8*)(H1b + (size_t)nC*DD + g*8);
        short8 pk;
        #pragma unroll
        for (int t=0;t<8;++t){
          float e = bf2f((ushort_t)sa[t]) + bf2f((ushort_t)sb[t]) + rd*w[gi][t];
          pk[t] = (short)f2bf(siluf(e));
        }
        *(short8*)((char*)ebuf + m*256 + ((g*16) ^ ((m&7)<<4))) = pk;
      }
    }
  }

  f32x4 acc[2][4];
  zacc(acc);
  __syncthreads();                                        // B1: ebuf+W2 ready

  // ---- GEMM2: silu(e1@W2+be2); att dot needs both col halves ---------------
  gemm_lds16(ebuf, Wbuf, mb, cbase, q, s, acc);
  {
    float wa[4], bb[4];
    #pragma unroll
    for (int ct=0;ct<4;++ct){ wa[ct]=Watt[cbase+16*ct+s]; bb[ct]=be2[cbase+16*ct+s]; }
    #pragma unroll
    for (int mt=0;mt<2;++mt){
      #pragma unroll
      for (int r=0;r<4;++r){
        float p = 0.f;
        #pragma unroll
        for (int ct=0;ct<4;++ct){
          float v = siluf(acc[mt][ct][r] + bb[ct]);
          acc[mt][ct][r] = v;
          p += v*wa[ct];
        }
        p += __shfl_xor(p,1); p += __shfl_xor(p,2);
        p += __shfl_xor(p,4); p += __shfl_xor(p,8);
        if (s==0) dscr[mb + mt*16 + q*4 + r][wn] = p;
      }
    }
  }
  __syncthreads();                                        // B2: dscr ready
  stage(wpre, 3, Wbuf, tid);                              // Wc1 (sigma)
  {
    const float bat = batt[0];
    #pragma unroll
    for (int mt=0;mt<2;++mt){
      #pragma unroll
      for (int r=0;r<4;++r){
        int m = mb + mt*16 + q*4 + r;
        float att = sigm(dscr[m][0] + dscr[m][1] + bat);
        short4v pk;
        #pragma unroll
        for (int ct=0;ct<4;++ct){
          acc[mt][ct][r] *= att;
          pk[ct]=(short)f2bf(acc[mt][ct][r]);
        }
        *(short4v*)((char*)ebuf + m*256 + ((16*s+8*wn) ^ ((m&7)<<4))) = pk;
        int e = we0 + m;
        if (e < EE){
          float* rp = ef_out + (size_t)e*DD + cbase + s;
          #pragma unroll
          for (int ct=0;ct<4;++ct) rp[16*ct] = acc[mt][ct][r];
        }
      }
    }
  }
  zacc(acc);
  __syncthreads();                                        // B3: ebuf(ef)+Wc1 ready

  // ---- GEMM3: cw = silu(ef@Wc1+bc1)@Wc2 ; trans = clip(cdiff*cw) -----------
  gemm_lds16(ebuf, Wbuf, mb, cbase, q, s, acc);
  {
    float wc[4], bb[4];
    #pragma unroll
    for (int ct=0;ct<4;++ct){ wc[ct]=Wc2[cbase+16*ct+s]; bb[ct]=bc1[cbase+16*ct+s]; }
    #pragma unroll
    for (int mt=0;mt<2;++mt){
      #pragma unroll
      for (int r=0;r<4;++r){
        float p = 0.f;
        #pragma unroll
        for (int ct=0;ct<4;++ct) p += siluf(acc[mt][ct][r]+bb[ct])*wc[ct];
        p += __shfl_xor(p,1); p += __shfl_xor(p,2);
        p += __shfl_xor(p,4); p += __shfl_xor(p,8);
        if (s==0) dscr[mb + mt*16 + q*4 + r][wn] = p;
      }
    }
  }
  __syncthreads();                                        // B4
  if (wn==0 && ln<32 && jg < EE){
    float p = dscr[mb+ln][0] + dscr[mb+ln][1];
    trans[(size_t)jg*3+0] = clamp10(cdx*p);
    trans[(size_t)jg*3+1] = clamp10(cdy*p);
    trans[(size_t)jg*3+2] = clamp10(cdz*p);
  }
}

// ---------------------------------------------------------------------------
// Fused aggregation + node MLP + coord finisher.
// Phase 1: each block aggregates ef rows (fp32 sums) for its 128 nodes into
//          LDS abuf (bf16, XOR-swizzled A-frag layout) + coord_out.
// Phase 2: h_out = h + silu([h,agg]@Wn1+bn1)@Wn2 + bn2 with pass-2 A from LDS.
// abuf is dead after pass-2 fragment loads -> reused as ubuf (LDS stays 64KB).
// ---------------------------------------------------------------------------
__launch_bounds__(512,4)
__global__ void k_aggnode(const float* __restrict__ h,
                          const float* __restrict__ ef,
                          const float* __restrict__ trans,
                          const int* __restrict__ cnt,
                          const int* __restrict__ rowstart,
                          const int* __restrict__ csr,
                          const float* __restrict__ coord,
                          const ushort_t* __restrict__ wpre,
                          const float* __restrict__ bn1,
                          const float* __restrict__ bn2,
                          float* __restrict__ hout,
                          float* __restrict__ coord_out)
{
  __shared__ ushort_t Wbuf[16384];
  __shared__ ushort_t abuf[16384];   // agg bf16 (phase 1) -> reused as ubuf
  const int tid = threadIdx.x;
  const int wv = tid>>6, ln = tid&63;
  const int wm = wv&3, wn = wv>>2;
  const int q = ln>>4, s = ln&15;
  const int cbase = wn*64;
  const int n0 = blockIdx.x*128;
  const int mb = wm*32;
  const int nd0 = min(n0 + mb + s,      NN-1);
  const int nd1 = min(n0 + mb + 16 + s, NN-1);

  // ---- phase 1: aggregate ef + trans for this block's 128 nodes -----------
  {
    const int hw = tid>>5;             // half-wave 0..15
    const int l  = tid&31;
    #pragma unroll 1
    for (int c=0; c<8; ++c){
      const int m = hw*8 + c;          // local node 0..127
      const int n = n0 + m;
      float a0=0.f,a1=0.f,a2=0.f,a3=0.f,ts=0.f;
      if (n < NN){
        const int rs = rowstart[n];
        const int deg = cnt[n];
        for (int j=0;j<deg;++j){
          const int e = csr[rs+j];
          f32x4 v = *(const f32x4*)(ef + (size_t)e*DD + l*4);
          a0+=v[0]; a1+=v[1]; a2+=v[2]; a3+=v[3];
          if (l<3) ts += trans[(size_t)e*3 + l];
        }
        if (l<3){
          float inv = 1.0f/(float)max(deg,1);
          coord_out[(size_t)n*3+l] = coord[(size_t)n*3+l] + clamp10(ts*inv);
        }
      }
      short4v pk = {(short)f2bf(a0),(short)f2bf(a1),(short)f2bf(a2),(short)f2bf(a3)};
      *(short4v*)((char*)abuf + m*256 + (((l>>1)*16) ^ ((m&7)<<4)) + (l&1)*8) = pk;
    }
  }
  stage(wpre, 4, Wbuf, tid);           // Wn1a (independent of abuf)
  __syncthreads();                                        // S1: abuf + W4 ready

  f32x4 acc[2][4];
  short8 af[2][4];
  zacc(acc);

  // pass 1: A = h (fp32->bf16)
  #pragma unroll
  for (int kc=0;kc<4;++kc){
    af[0][kc] = ldcvt(h + (size_t)nd0*DD + kc*32 + q*8);
    af[1][kc] = ldcvt(h + (size_t)nd1*DD + kc*32 + q*8);
  }
  gemm_b16(af, Wbuf, cbase, q, s, acc);

  // pass 2 A-frags from LDS abuf (same XOR layout as Wbuf rows)
  #pragma unroll
  for (int kc=0;kc<4;++kc){
    const int koff = (kc*64+q*16) ^ ((s&7)<<4);
    af[0][kc] = *(const short8*)((const char*)abuf + (mb+s)*256 + koff);
    af[1][kc] = *(const short8*)((const char*)abuf + (mb+16+s)*256 + koff);
  }
  __syncthreads();                                        // S2: W4 + abuf reads done
  stage(wpre, 5, Wbuf, tid);           // Wn1b
  __syncthreads();                                        // S3
  gemm_b16(af, Wbuf, cbase, q, s, acc);
  __syncthreads();                                        // S4: W5 reads done

  // u = silu(acc + bn1) -> sigma-pack into abuf (now ubuf); stage Wn2
  stage(wpre, 6, Wbuf, tid);
  {
    float bb[4];
    #pragma unroll
    for (int ct=0;ct<4;++ct) bb[ct]=bn1[cbase+16*ct+s];
    #pragma unroll
    for (int mt=0;mt<2;++mt){
      #pragma unroll
      for (int r=0;r<4;++r){
        int m = mb + mt*16 + q*4 + r;
        short4v pk;
        #pragma unroll
        for (int ct=0;ct<4;++ct) pk[ct]=(short)f2bf(siluf(acc[mt][ct][r]+bb[ct]));
        *(short4v*)((char*)abuf + m*256 + ((16*s+8*wn) ^ ((m&7)<<4))) = pk;
      }
    }
  }
  zacc(acc);
  __syncthreads();                                        // S5: ubuf + W6 ready

  gemm_lds16(abuf, Wbuf, mb, cbase, q, s, acc);

  {
    float bb[4];
    #pragma unroll
    for (int ct=0;ct<4;++ct) bb[ct]=bn2[cbase+16*ct+s];
    #pragma unroll
    for (int mt=0;mt<2;++mt){
      #pragma unroll
      for (int r=0;r<4;++r){
        int n = n0 + mb + mt*16 + q*4 + r;
        if (n < NN){
          const float* hp = h + (size_t)n*DD + cbase + s;
          float* op = hout + (size_t)n*DD + cbase + s;
          #pragma unroll
          for (int ct=0;ct<4;++ct) op[16*ct] = hp[16*ct] + acc[mt][ct][r] + bb[ct];
        }
      }
    }
  }
}

// ---------------------------------------------------------------------------
extern "C" void kernel_launch(void* const* d_in, const int* in_sizes, int n_in,
                              void* d_out, int out_size, void* d_ws, size_t ws_size,
                              hipStream_t stream)
{
  const float* h    = (const float*)d_in[0];
  const int*   eidx = (const int*)  d_in[1];
  const float* coord= (const float*)d_in[2];
  const float* We1  = (const float*)d_in[3];
  const float* be1  = (const float*)d_in[4];
  const float* We2  = (const float*)d_in[5];
  const float* be2  = (const float*)d_in[6];
  const float* Watt = (const float*)d_in[7];
  const float* batt = (const float*)d_in[8];
  const float* Wc1  = (const float*)d_in[9];
  const float* bc1  = (const float*)d_in[10];
  const float* Wc2  = (const float*)d_in[11];
  const float* Wn1  = (const float*)d_in[12];
  const float* bn1  = (const float*)d_in[13];
  const float* Wn2  = (const float*)d_in[14];
  const float* bn2  = (const float*)d_in[15];

  float* hout     = (float*)d_out;
  float* coordout = hout + (size_t)NN*DD;              // +6,400,000
  float* efout    = coordout + (size_t)NN*3;           // +6,550,000

  char* ws = (char*)d_ws;
  float*    trans = (float*)(ws);                       // E*3 f32 = 6,000,000 B
  int*   cnt      = (int*)  (ws + 6000000);             // N ints  =   200,000 B
  int*   gbase    = (int*)  (ws + 6200000);             // 1 int (+pad)
  int*   cursor   = (int*)  (ws + 6200064);             // N
  int*   rowstart = (int*)  (ws + 6400064);             // N
  int*   csr      = (int*)  (ws + 6600064);             // E
  ushort_t* wpre  = (ushort_t*)(ws + 8600064);          // 7*32768 B -> 8,829,440
  ushort_t* H1a   = (ushort_t*)(ws + 8829440);          // N*128 bf16 = 12,800,000 B
  ushort_t* H1b   = (ushort_t*)(ws + 21629440);         // N*128 bf16 -> ends 34,429,440

  hipMemsetAsync(cnt, 0, 200064, stream);               // cnt + gbase
  k_prep_count  <<<2402,256, 0, stream>>>(We1, We2, Wc1, Wn1, Wn2, wpre, eidx, cnt);
  k_offsets     <<<196, 256, 0, stream>>>(cnt, gbase, rowstart, cursor);
  k_scatter_pre1<<<1368,512, 0, stream>>>(eidx, cursor, csr, h, wpre, be1, H1a, H1b);
  k_edge        <<<3907,512, 0, stream>>>(H1a, H1b, eidx, coord, We1, be2, Watt,
                                          batt, bc1, Wc2, wpre, efout, trans);
  k_aggnode     <<<391, 512, 0, stream>>>(h, efout, trans, cnt, rowstart, csr,
                                          coord, wpre, bn1, bn2, hout, coordout);
}